// Round 5
// baseline (500.825 us; speedup 1.0000x reference)
//
#include <hip/hip_runtime.h>

typedef unsigned short u16; typedef unsigned int u32; typedef unsigned long long u64;
typedef __attribute__((ext_vector_type(8))) short short8;
typedef __attribute__((ext_vector_type(16))) float f32x16;

#define HW 16384

// fp32 ws region (float index)
#define RED_B  0
#define C1E_B  128
#define C2_B   160
#define OUT_B  416
#define BN_SC  480
#define BN_SH  544
// byte offsets in ws
#define FLAG_OFF   4096
#define RWB_OFF    8192      // bf16 weights, fragment-major [otile][s][lane][8]
#define C1B_OFF    73728     // bf16 [32][128]
#define EMBB_OFF   81920     // bf16 [32][256]
#define OUTB_OFF   98304     // bf16 [64][128]
#define C2PB_OFF   114688    // bf16 [256][288] tap-major (zeros for oc>=200)
#define CAT2_OFF   524288    // bf16 [8*16384][128] pixel-major
#define MIX_OFF    34078720  // bf16 [8*16384][32]  pixel-major

__device__ __forceinline__ float bf2f(u16 x){ u32 u=((u32)x)<<16; float f; __builtin_memcpy(&f,&u,4); return f; }
__device__ __forceinline__ u16 f2bf(float f){ u32 u; __builtin_memcpy(&u,&f,4); return (u16)((u + 0x7fffu + ((u>>16)&1u))>>16); }
__device__ __forceinline__ u32 pk2(float a, float b){ return (u32)f2bf(a) | ((u32)f2bf(b)<<16); }
__device__ __forceinline__ float lrelu(float x){ return x>0.f ? x : 0.01f*x; }

template<int M> __device__ __forceinline__ u16 ldb(const void* p, size_t i){
    if (M==1) return ((const u16*)p)[i];
    return f2bf(((const float*)p)[i]);
}
template<int M> __device__ __forceinline__ float ldf(const void* p, size_t i){
    if (M==1) return bf2f(((const u16*)p)[i]);
    return ((const float*)p)[i];
}
// bijective swizzle over pixel-octet AND pixel-within-octet
__device__ __forceinline__ int swz(int p){ return ((p>>1) ^ (p>>3)) & 7; }

// ---------------- dtype detector ----------------
__global__ void detect_kernel(const void* __restrict__ emb, u32* __restrict__ flag){
    int tid = threadIdx.x;
    const u16* p = (const u16*)emb;
    int e = (p[tid*2] >> 7) & 0xFF;
    u64 m = __ballot(e >= 100 && e <= 140);
    if (tid == 0) *flag = (__popcll(m) >= 32) ? 1u : 0u;
}

// ---------------- prep ----------------
template<int M>
__device__ __forceinline__ void prep_body(
    const void* rw, const void* rb, const void* c1w, const void* c1b,
    const void* c2w, const void* c2b, const void* ew, const void* eb,
    const void* ow, const void* ob, const void* gam, const void* bet,
    const void* mn, const void* vr, char* ws)
{
    float* wf = (float*)ws;
    int i = blockIdx.x*256 + threadIdx.x;
    if (i < 32768) {
        // reduce weights -> fragment-major: [otile(4)][s(16)][lane(64)][8]
        int o = i>>8, ic = i&255;
        int s = ic>>4, qq = (ic>>3)&1, e = ic&7;
        int dst = (((o>>5)*16 + s)*64 + qq*32 + (o&31))*8 + e;
        ((u16*)(ws+RWB_OFF))[dst] = ldb<M>(rw, i);
    }
    else if (i < 36864)  ((u16*)(ws+C1B_OFF))[i-32768] = ldb<M>(c1w, i-32768);
    else if (i < 45056)  ((u16*)(ws+EMBB_OFF))[i-36864] = ldb<M>(ew, i-36864);
    else if (i < 53248)  ((u16*)(ws+OUTB_OFF))[i-45056] = ldb<M>(ow, i-45056);
    else if (i < 126976) {
        int j = i-53248; int o = j/288, k = j - o*288;
        int tap = k>>5, ic = k&31;
        u16 v = 0;
        if (o < 200) v = ldb<M>(c2w, (size_t)o*288 + ic*9 + tap);
        ((u16*)(ws+C2PB_OFF))[j] = v;
    }
    else if (i < 127584) {
        int j = i-126976;
        if (j < 128) wf[RED_B+j] = ldf<M>(rb, j);
        else if (j < 160) wf[C1E_B+j-128] = ldf<M>(c1b, j-128) + ldf<M>(eb, j-128);
        else if (j < 416) { int o = j-160; wf[C2_B+o] = (o<200) ? ldf<M>(c2b,o) : 0.f; }
        else if (j < 480) wf[OUT_B+j-416] = ldf<M>(ob, j-416);
        else if (j < 544) { int c=j-480; wf[BN_SC+c] = ldf<M>(gam,c) * rsqrtf(ldf<M>(vr,c)+1e-5f); }
        else { int c=j-544; wf[BN_SH+c] = ldf<M>(bet,c) - ldf<M>(mn,c)*ldf<M>(gam,c)*rsqrtf(ldf<M>(vr,c)+1e-5f); }
    }
}

__global__ __launch_bounds__(256) void k_prep(
    const void* rw, const void* rb, const void* c1w, const void* c1b,
    const void* c2w, const void* c2b, const void* ew, const void* eb,
    const void* ow, const void* ob, const void* gam, const void* bet,
    const void* mn, const void* vr, char* ws, const u32* __restrict__ flag)
{
    if (*flag) prep_body<1>(rw,rb,c1w,c1b,c2w,c2b,ew,eb,ow,ob,gam,bet,mn,vr,ws);
    else       prep_body<0>(rw,rb,c1w,c1b,c2w,c2b,ew,eb,ow,ob,gam,bet,mn,vr,ws);
}

// ---------------- fused reduce + mix ----------------
// grid 2048, 256 thr: one 64-px chunk per block.
// ALL HBM loads (emb + lo/hi) are issued at kernel top and pinned there with a
// compiler memory barrier -> ~16x32B outstanding per thread, ONE exposed latency.
// P2 (emb->LDS) then touches no global memory.
template<int M>
__device__ __forceinline__ void rm_body(
    const void* __restrict__ hi, const void* __restrict__ lo, const void* __restrict__ emb,
    const u16* __restrict__ rwB, const u16* __restrict__ c1B, const u16* __restrict__ embB,
    const float* __restrict__ wf, u16* __restrict__ cat2, u16* __restrict__ mixt,
    u16* At, u16* c2l)
{
    const int tid = threadIdx.x, wvi = tid>>6, lane = tid&63;
    const int col = lane&31, q = lane>>5;
    const int gpx = blockIdx.x*64;
    const int b = gpx>>14, p0 = gpx&16383;
    const int h = p0>>7, w0 = p0&127;
    const int co = tid>>3, po = tid&7;   // channel-octet 0..31, pixel-octet 0..7

    // ---- issue ALL HBM loads ----
    float rawe[8][8]; u32 Re[8][4];
    {
        size_t ebase = ((size_t)(b*256 + 8*co))*HW + p0 + 8*po;
        if (M==1){
#pragma unroll
            for (int j=0;j<8;j++)
                __builtin_memcpy(&Re[j][0], (const u16*)emb + ebase + (size_t)j*HW, 16);
        } else {
#pragma unroll
            for (int j=0;j<8;j++)
                __builtin_memcpy(&rawe[j][0], (const float*)emb + ebase + (size_t)j*HW, 32);
        }
    }
    float rawl[8][8]; u32 Rl[8][4];
    float rE[8][4], rO[8][4]; u32 E[8][2], O[8][2];
    const int cc0 = (co-28)*8, h2 = (h&1)*2;
    if (co < 28) {
        size_t lbase = ((size_t)(b*224 + 8*co))*HW + p0 + 8*po;
        if (M==1){
#pragma unroll
            for (int j=0;j<8;j++)
                __builtin_memcpy(&Rl[j][0], (const u16*)lo + lbase + (size_t)j*HW, 16);
        } else {
#pragma unroll
            for (int j=0;j<8;j++)
                __builtin_memcpy(&rawl[j][0], (const float*)lo + lbase + (size_t)j*HW, 32);
        }
    } else {
#pragma unroll
        for (int j=0;j<8;j++){
            int hc = (cc0+j)*4 + h2;
            size_t src = ((size_t)(b*128 + hc))*4096 + (size_t)(h>>1)*64 + (w0>>1) + 4*po;
            if (M==1){
                __builtin_memcpy(&E[j][0], (const u16*)hi + src, 8);
                __builtin_memcpy(&O[j][0], (const u16*)hi + src + 4096, 8);
            } else {
                __builtin_memcpy(&rE[j][0], (const float*)hi + src, 16);
                __builtin_memcpy(&rO[j][0], (const float*)hi + src + 4096, 16);
            }
        }
    }
    asm volatile("" ::: "memory");   // pin all issues above; no sinking to uses

    // pack emb early (frees 64 raw VGPRs before P1)
    if (M==0){
#pragma unroll
        for (int j=0;j<8;j++)
#pragma unroll
        for (int m=0;m<4;m++) Re[j][m] = pk2(rawe[j][2*m], rawe[j][2*m+1]);
    }

    // ---- P0: transpose + stage concat into At ----
    u32 W[8][4];
    if (co < 28) {
        if (M==0){
#pragma unroll
            for (int j=0;j<8;j++)
#pragma unroll
            for (int m=0;m<4;m++) Rl[j][m] = pk2(rawl[j][2*m], rawl[j][2*m+1]);
        }
#pragma unroll
        for (int p=0;p<8;p++){
            const int u = p>>1, hf = p&1;
#pragma unroll
            for (int m=0;m<4;m++){
                u32 A0 = Rl[2*m][u], A1 = Rl[2*m+1][u];
                W[p][m] = hf ? ((A0>>16) | (A1 & 0xffff0000u))
                             : ((A0 & 0xffffu) | (A1<<16));
            }
        }
        const int ch = co + 4;
#pragma unroll
        for (int p=0;p<8;p++){
            int pg = 8*po + p;
            __builtin_memcpy(At + pg*264 + ((ch ^ swz(pg))<<3), &W[p][0], 16);
        }
    } else {
        if (M==0){
#pragma unroll
            for (int j=0;j<8;j++){
                E[j][0] = pk2(rE[j][0], rE[j][1]); E[j][1] = pk2(rE[j][2], rE[j][3]);
                O[j][0] = pk2(rO[j][0], rO[j][1]); O[j][1] = pk2(rO[j][2], rO[j][3]);
            }
        }
#pragma unroll
        for (int p=0;p<8;p++){
            const int k = p>>1, u = k>>1, hf = k&1;
#pragma unroll
            for (int m=0;m<4;m++){
                u32 A0, A1;
                if (p&1){ A0 = O[2*m][u]; A1 = O[2*m+1][u]; }
                else    { A0 = E[2*m][u]; A1 = E[2*m+1][u]; }
                W[p][m] = hf ? ((A0>>16) | (A1 & 0xffff0000u))
                             : ((A0 & 0xffffu) | (A1<<16));
            }
        }
        const int ch = co - 28;
#pragma unroll
        for (int p=0;p<8;p++){
            int pg = 8*po + p;
            __builtin_memcpy(At + pg*264 + ((ch ^ swz(pg))<<3), &W[p][0], 16);
        }
    }
    __syncthreads();   // A: At(concat) ready

    // ---- P1: reduce MFMA (wave = 32px x 64oc) ----
    {
        const int rt = (wvi>>1)*32, nc0 = (wvi&1)*64;
        const int pp = rt + col, sw = swz(pp);
        const u16* arow = At + pp*264;
        const int ot0 = (wvi&1)*2;

        f32x16 acc0, acc1;
#pragma unroll
        for (int r=0;r<16;r++){ acc0[r]=0.f; acc1[r]=0.f; }

        short8 Bb[2][8];
#pragma unroll
        for (int nt=0;nt<2;nt++)
#pragma unroll
        for (int s=0;s<8;s++)
            __builtin_memcpy(&Bb[nt][s], rwB + (((size_t)((ot0+nt)*16 + s))*64 + lane)*8, 16);
#pragma unroll
        for (int s=0;s<8;s++){
            short8 a; __builtin_memcpy(&a, arow + (((2*s+q)^sw)<<3), 16);
            acc0 = __builtin_amdgcn_mfma_f32_32x32x16_bf16(a, Bb[0][s], acc0, 0,0,0);
            acc1 = __builtin_amdgcn_mfma_f32_32x32x16_bf16(a, Bb[1][s], acc1, 0,0,0);
        }
#pragma unroll
        for (int nt=0;nt<2;nt++)
#pragma unroll
        for (int s=0;s<8;s++)
            __builtin_memcpy(&Bb[nt][s], rwB + (((size_t)((ot0+nt)*16 + 8+s))*64 + lane)*8, 16);
#pragma unroll
        for (int s=8;s<16;s++){
            short8 a; __builtin_memcpy(&a, arow + (((2*s+q)^sw)<<3), 16);
            acc0 = __builtin_amdgcn_mfma_f32_32x32x16_bf16(a, Bb[0][s-8], acc0, 0,0,0);
            acc1 = __builtin_amdgcn_mfma_f32_32x32x16_bf16(a, Bb[1][s-8], acc1, 0,0,0);
        }

#pragma unroll
        for (int nt=0; nt<2; nt++){
            int oc = nc0 + nt*32 + col;
            float bias = wf[RED_B + oc];
#pragma unroll
            for (int r=0;r<16;r++){
                int row = (r&3) + 8*(r>>2) + 4*q;
                int px = rt + row;
                u16 bv = f2bf((nt ? acc1[r] : acc0[r]) + bias);
                cat2[((size_t)(gpx + px))*128 + oc] = bv;
                c2l[px*136 + (((oc>>3) ^ swz(px))<<3) + (oc&7)] = bv;
            }
        }
    }
    __syncthreads();   // B: concat reads + c2l writes complete

    // ---- P2: transpose Re -> At (no HBM access) ----
#pragma unroll
    for (int p=0;p<8;p++){
        const int u = p>>1, hf = p&1;
#pragma unroll
        for (int m=0;m<4;m++){
            u32 A0 = Re[2*m][u], A1 = Re[2*m+1][u];
            W[p][m] = hf ? ((A0>>16) | (A1 & 0xffff0000u))
                         : ((A0 & 0xffffu) | (A1<<16));
        }
    }
#pragma unroll
    for (int p=0;p<8;p++){
        int pg = 8*po + p;
        __builtin_memcpy(At + pg*264 + ((co ^ swz(pg))<<3), &W[p][0], 16);
    }
    __syncthreads();   // C: At(emb) + c2l ready

    // ---- P3: mix MFMA, K-split across wave pairs ----
    const int rt2 = wvi>>1, q2 = wvi&1;
    const int pp2 = rt2*32 + col, sw2 = swz(pp2);
    const u16* arow136 = c2l + pp2*136;
    const u16* arow264 = At + pp2*264;

    f32x16 macc;
#pragma unroll
    for (int r=0;r<16;r++) macc[r]=0.f;

    if (q2 == 0){
        short8 Bc[8];
#pragma unroll
        for (int s=0;s<8;s++)
            __builtin_memcpy(&Bc[s], c1B + (size_t)col*128 + s*16 + q*8, 16);
#pragma unroll
        for (int s=0;s<8;s++){
            short8 a; __builtin_memcpy(&a, arow136 + (((2*s+q)^sw2)<<3), 16);
            macc = __builtin_amdgcn_mfma_f32_32x32x16_bf16(a, Bc[s], macc, 0,0,0);
        }
        short8 Be[4];
#pragma unroll
        for (int s=0;s<4;s++)
            __builtin_memcpy(&Be[s], embB + (size_t)col*256 + s*16 + q*8, 16);
#pragma unroll
        for (int s=0;s<4;s++){
            short8 a; __builtin_memcpy(&a, arow264 + (((2*s+q)^sw2)<<3), 16);
            macc = __builtin_amdgcn_mfma_f32_32x32x16_bf16(a, Be[s], macc, 0,0,0);
        }
    } else {
        short8 Be[12];
#pragma unroll
        for (int s=0;s<12;s++)
            __builtin_memcpy(&Be[s], embB + (size_t)col*256 + (4+s)*16 + q*8, 16);
#pragma unroll
        for (int s=0;s<12;s++){
            int ks = 4 + s;
            short8 a; __builtin_memcpy(&a, arow264 + (((2*ks+q)^sw2)<<3), 16);
            macc = __builtin_amdgcn_mfma_f32_32x32x16_bf16(a, Be[s], macc, 0,0,0);
        }
    }
    __syncthreads();   // D: all MFMA reads of At/c2l done

    // ---- P4: combine partner accs via LDS (reuse At as f32 buffer) ----
    float* exch = (float*)At;
    if (q2 == 1){
#pragma unroll
        for (int r=0;r<16;r++){
            int row = (r&3) + 8*(r>>2) + 4*q;
            exch[rt2*1024 + row*32 + col] = macc[r];
        }
    }
    __syncthreads();   // E
    if (q2 == 0){
        float bias = wf[C1E_B + col];
#pragma unroll
        for (int r=0;r<16;r++){
            int row = (r&3) + 8*(r>>2) + 4*q;
            float v = macc[r] + exch[rt2*1024 + row*32 + col] + bias;
            mixt[((size_t)(gpx + rt2*32 + row))*32 + col] = f2bf(lrelu(v));
        }
    }
}

__global__ __launch_bounds__(256,3) void k_rm(
    const void* __restrict__ hi, const void* __restrict__ lo, const void* __restrict__ emb,
    const u16* __restrict__ rwB, const u16* __restrict__ c1B, const u16* __restrict__ embB,
    const float* __restrict__ wf, u16* __restrict__ cat2, u16* __restrict__ mixt,
    const u32* __restrict__ flag)
{
    __shared__ u16 At[64*264];    // 33792 B (concat, then emb, then f32 exch)
    __shared__ u16 c2l[64*136];   // 17408 B (cat2 tile, swizzled)
    if (*flag) rm_body<1>(hi, lo, emb, rwB, c1B, embB, wf, cat2, mixt, At, c2l);
    else       rm_body<0>(hi, lo, emb, rwB, c1B, embB, wf, cat2, mixt, At, c2l);
}

// ---------------- fused conv2 + involution + out conv + BN + lrelu ----------------
// T14 in the g-loop: cat2-halo loads issued into regs, conv2 MFMA covers their
// latency, LDS commit after.
template<int M>
__device__ __forceinline__ void inv_body(
    const u16* __restrict__ cat2, const u16* __restrict__ mixt,
    const u16* __restrict__ c2B, const u16* __restrict__ outB,
    const float* __restrict__ wf, void* __restrict__ out,
    u16* halo_m, u16* wgt_l, u16* halo_c, u16* og)
{
    const int tid = threadIdx.x, wvi = tid>>6, lane = tid&63;
    const int col = lane&31, q = lane>>5;
    const int b = blockIdx.y, ty = blockIdx.x>>3, tx = blockIdx.x&7;
    const int py = tid>>4, px = tid&15;

    f32x16 acc[2][2];
#pragma unroll
    for (int i=0;i<2;i++)
#pragma unroll
    for (int j=0;j<2;j++)
#pragma unroll
    for (int r=0;r<16;r++) acc[i][j][r] = 0.f;

    // ---- stage mixt halo 18x18 x 32ch, stride 40 u16 ----
#pragma unroll
    for (int i=0;i<6;i++){
        int idx = tid + i*256;
        if (idx < 1296){
            int point = idx>>2, cq = idx&3;
            int y = ty*16 + point/18 - 1, x = tx*16 + point%18 - 1;
            short8 v;
            if (y>=0 && y<128 && x>=0 && x<128)
                __builtin_memcpy(&v, mixt + ((size_t)(b*HW + y*128 + x))*32 + cq*8, 16);
            else { short z=0; v = (short8){z,z,z,z,z,z,z,z}; }
            *(short8*)(halo_m + point*40 + cq*8) = v;
        }
    }
    __syncthreads();   // halo_m ready

#pragma unroll 1
    for (int g=0; g<8; g++){
        __syncthreads();   // prev group's halo_c/wgt_l/og reads complete

        const int o = g*25 + col;
        short8 Bf[18];
#pragma unroll
        for (int s=0;s<18;s++)
            __builtin_memcpy(&Bf[s], c2B + (size_t)o*288 + s*16 + q*8, 16);

        // issue cat2 halo loads into regs; LDS commit deferred past conv2
        short8 hv[4];
#pragma unroll
        for (int i=0;i<4;i++){
            int idx = tid + i*256;
            short z=0; hv[i] = (short8){z,z,z,z,z,z,z,z};
            if (idx < 800){
                int point = idx>>1, cq = idx&1;
                int y = ty*16 + point/20 - 2, x = tx*16 + point%20 - 2;
                if (y>=0 && y<128 && x>=0 && x<128)
                    __builtin_memcpy(&hv[i], cat2 + ((size_t)(b*HW + y*128 + x))*128 + g*16 + cq*8, 16);
            }
        }
        asm volatile("" ::: "memory");   // pin load issue above the MFMA block

        f32x16 c0, c1;
#pragma unroll
        for (int r=0;r<16;r++){ c0[r]=0.f; c1[r]=0.f; }
        const int p0 = wvi*64 + col, p1 = p0 + 32;
        const int pya = p0>>4, pxa = p0&15, pyb = p1>>4, pxb = p1&15;
#pragma unroll
        for (int s=0;s<18;s++){
            int tap = s>>1, ih = s&1;
            int dy = tap/3, dx = tap%3;
            short8 a0, a1;
            __builtin_memcpy(&a0, halo_m + ((pya+dy)*18 + pxa+dx)*40 + ih*16 + q*8, 16);
            __builtin_memcpy(&a1, halo_m + ((pyb+dy)*18 + pxb+dx)*40 + ih*16 + q*8, 16);
            c0 = __builtin_amdgcn_mfma_f32_32x32x16_bf16(a0, Bf[s], c0, 0,0,0);
            c1 = __builtin_amdgcn_mfma_f32_32x32x16_bf16(a1, Bf[s], c1, 0,0,0);
        }
        {
            float bias = wf[C2_B + o];
#pragma unroll
            for (int rt2=0; rt2<2; rt2++){
                int mb = wvi*64 + rt2*32;
#pragma unroll
                for (int r=0;r<16;r+=2){
                    int row0 = (r&3) + 8*(r>>2) + 4*q;
                    float v0 = (rt2 ? c1[r]   : c0[r])   + bias;
                    float v1 = (rt2 ? c1[r+1] : c0[r+1]) + bias;
                    u32 pkv = (u32)f2bf(v0) | ((u32)f2bf(v1)<<16);
                    *(u32*)(wgt_l + (size_t)col*264 + mb + row0) = pkv;
                }
            }
        }
        // commit cat2 halo to LDS (loads have drained under conv2)
#pragma unroll
        for (int i=0;i<4;i++){
            int idx = tid + i*256;
            if (idx < 800){
                int point = idx>>1, cq = idx&1;
                *(short8*)(halo_c + point*16 + cq*8) = hv[i];
            }
        }
        __syncthreads();   // halo_c + wgt_l ready

        float wvv[25];
#pragma unroll
        for (int t=0;t<25;t++) wvv[t] = bf2f(wgt_l[t*264 + tid]);

        float a16[16];
#pragma unroll
        for (int cc=0;cc<16;cc++) a16[cc]=0.f;
#pragma unroll
        for (int t=0;t<25;t++){
            int dy = t/5, dx = t%5;
            u32 vv[8];
            __builtin_memcpy(vv, halo_c + ((py+dy)*20 + px+dx)*16, 32);
            float wt = wvv[t];
#pragma unroll
            for (int r=0;r<8;r++){
                u32 u = vv[r];
                u32 ulo = u<<16, uhi = u & 0xffff0000u;
                float x0, x1;
                __builtin_memcpy(&x0,&ulo,4); __builtin_memcpy(&x1,&uhi,4);
                a16[2*r]   += wt*x0;
                a16[2*r+1] += wt*x1;
            }
        }
        u32 pk[8];
#pragma unroll
        for (int r=0;r<8;r++) pk[r] = (u32)f2bf(a16[2*r]) | ((u32)f2bf(a16[2*r+1])<<16);
        __builtin_memcpy(og + tid*16, pk, 32);
        __syncthreads();   // og ready

        short8 bo0, bo1;
        __builtin_memcpy(&bo0, outB + (size_t)(col)*128      + g*16 + q*8, 16);
        __builtin_memcpy(&bo1, outB + (size_t)(32+col)*128   + g*16 + q*8, 16);
#pragma unroll
        for (int rt2=0; rt2<2; rt2++){
            int prow = (wvi*2 + rt2)*32 + col;
            short8 a; __builtin_memcpy(&a, og + prow*16 + q*8, 16);
            acc[rt2][0] = __builtin_amdgcn_mfma_f32_32x32x16_bf16(a, bo0, acc[rt2][0], 0,0,0);
            acc[rt2][1] = __builtin_amdgcn_mfma_f32_32x32x16_bf16(a, bo1, acc[rt2][1], 0,0,0);
        }
    }
#pragma unroll
    for (int rt2=0; rt2<2; rt2++)
#pragma unroll
    for (int nt=0; nt<2; nt++){
        int oc = nt*32 + col;
        float bias = wf[OUT_B+oc], sc = wf[BN_SC+oc], sh = wf[BN_SH+oc];
#pragma unroll
        for (int r=0;r<16;r++){
            int row = (r&3) + 8*(r>>2) + 4*q;
            int p = (wvi*2 + rt2)*32 + row;
            int yy = ty*16 + (p>>4), xx = tx*16 + (p&15);
            float v = lrelu((acc[rt2][nt][r] + bias)*sc + sh);
            size_t oidx = ((size_t)(b*64 + oc))*HW + yy*128 + xx;
            if (M==1) ((u16*)out)[oidx] = f2bf(v);
            else ((float*)out)[oidx] = v;
        }
    }
}

__global__ __launch_bounds__(256,2) void k_inv(
    const u16* __restrict__ cat2, const u16* __restrict__ mixt,
    const u16* __restrict__ c2B, const u16* __restrict__ outB,
    const float* __restrict__ wf, void* __restrict__ out, const u32* __restrict__ flag)
{
    __shared__ u16 halo_m[324*40];   // 25920 B
    __shared__ u16 wgt_l[32*264];    // 16896 B
    __shared__ u16 halo_c[400*16];   // 12800 B
    __shared__ u16 og[256*16];       //  8192 B  -> total 63808 B
    if (*flag) inv_body<1>(cat2, mixt, c2B, outB, wf, out, halo_m, wgt_l, halo_c, og);
    else       inv_body<0>(cat2, mixt, c2B, outB, wf, out, halo_m, wgt_l, halo_c, og);
}

extern "C" void kernel_launch(void* const* d_in, const int* in_sizes, int n_in,
                              void* d_out, int out_size, void* d_ws, size_t ws_size,
                              hipStream_t stream) {
    const void* hi  = d_in[0];
    const void* lo  = d_in[1];
    const void* emb = d_in[2];
    char* ws = (char*)d_ws;
    float* wf = (float*)ws;
    u32* flag = (u32*)(ws + FLAG_OFF);
    u16* cat2 = (u16*)(ws + CAT2_OFF);
    u16* mixt = (u16*)(ws + MIX_OFF);

    detect_kernel<<<1, 64, 0, stream>>>(emb, flag);

    k_prep<<<499,256,0,stream>>>(d_in[3],d_in[4],d_in[5],d_in[6],d_in[7],d_in[8],
        d_in[9],d_in[10],d_in[11],d_in[12],d_in[13],d_in[14],d_in[15],d_in[16], ws, flag);

    k_rm<<<2048,256,0,stream>>>(hi, lo, emb, (const u16*)(ws+RWB_OFF),
                                (const u16*)(ws+C1B_OFF), (const u16*)(ws+EMBB_OFF),
                                wf, cat2, mixt, flag);

    k_inv<<<dim3(64,8),256,0,stream>>>(cat2, mixt, (const u16*)(ws+C2PB_OFF),
                                       (const u16*)(ws+OUTB_OFF), wf, d_out, flag);
}

// Round 6
// 396.157 us; speedup vs baseline: 1.2642x; 1.2642x over previous
//
#include <hip/hip_runtime.h>

typedef unsigned short u16; typedef unsigned int u32; typedef unsigned long long u64;
typedef __attribute__((ext_vector_type(8))) short short8;
typedef __attribute__((ext_vector_type(16))) float f32x16;

#define HW 16384

// fp32 ws region (float index)
#define RED_B  0
#define C1E_B  128
#define C2_B   160
#define OUT_B  416
#define BN_SC  480
#define BN_SH  544
// byte offsets in ws
#define FLAG_OFF   4096
#define RWB_OFF    8192      // bf16 weights, fragment-major [otile][s][lane][8]
#define C1B_OFF    73728     // bf16 [32][128]
#define EMBB_OFF   81920     // bf16 [32][256]
#define OUTB_OFF   98304     // bf16 [64][128]
#define C2PB_OFF   114688    // bf16 [256][288] tap-major (zeros for oc>=200)
#define CAT2_OFF   524288    // bf16 [8*16384][128] pixel-major
#define MIX_OFF    34078720  // bf16 [8*16384][32]  pixel-major

__device__ __forceinline__ float bf2f(u16 x){ u32 u=((u32)x)<<16; float f; __builtin_memcpy(&f,&u,4); return f; }
__device__ __forceinline__ u16 f2bf(float f){ u32 u; __builtin_memcpy(&u,&f,4); return (u16)((u + 0x7fffu + ((u>>16)&1u))>>16); }
__device__ __forceinline__ u32 pk2(float a, float b){ return (u32)f2bf(a) | ((u32)f2bf(b)<<16); }
__device__ __forceinline__ float lrelu(float x){ return x>0.f ? x : 0.01f*x; }

template<int M> __device__ __forceinline__ u16 ldb(const void* p, size_t i){
    if (M==1) return ((const u16*)p)[i];
    return f2bf(((const float*)p)[i]);
}
template<int M> __device__ __forceinline__ float ldf(const void* p, size_t i){
    if (M==1) return bf2f(((const u16*)p)[i]);
    return ((const float*)p)[i];
}
// bijective swizzle over pixel-octet AND pixel-within-octet
__device__ __forceinline__ int swz(int p){ return ((p>>1) ^ (p>>3)) & 7; }

// batched load of 8 channels x 8 px (bf16-packed pairs). Loads issued before converts.
template<int M>
__device__ __forceinline__ void load8x8(const void* p, size_t base, size_t stride, u32 R[8][4]){
    if (M==1){
#pragma unroll
        for (int j=0;j<8;j++)
            __builtin_memcpy(&R[j][0], (const u16*)p + base + (size_t)j*stride, 16);
    } else {
        float raw[8][8];
#pragma unroll
        for (int j=0;j<8;j++)
            __builtin_memcpy(&raw[j][0], (const float*)p + base + (size_t)j*stride, 32);
#pragma unroll
        for (int j=0;j<8;j++)
#pragma unroll
        for (int m=0;m<4;m++) R[j][m] = pk2(raw[j][2*m], raw[j][2*m+1]);
    }
}

// ---------------- dtype detector ----------------
__global__ void detect_kernel(const void* __restrict__ emb, u32* __restrict__ flag){
    int tid = threadIdx.x;
    const u16* p = (const u16*)emb;
    int e = (p[tid*2] >> 7) & 0xFF;
    u64 m = __ballot(e >= 100 && e <= 140);
    if (tid == 0) *flag = (__popcll(m) >= 32) ? 1u : 0u;
}

// ---------------- prep ----------------
template<int M>
__device__ __forceinline__ void prep_body(
    const void* rw, const void* rb, const void* c1w, const void* c1b,
    const void* c2w, const void* c2b, const void* ew, const void* eb,
    const void* ow, const void* ob, const void* gam, const void* bet,
    const void* mn, const void* vr, char* ws)
{
    float* wf = (float*)ws;
    int i = blockIdx.x*256 + threadIdx.x;
    if (i < 32768) {
        // reduce weights -> fragment-major: [otile(4)][s(16)][lane(64)][8]
        int o = i>>8, ic = i&255;
        int s = ic>>4, qq = (ic>>3)&1, e = ic&7;
        int dst = (((o>>5)*16 + s)*64 + qq*32 + (o&31))*8 + e;
        ((u16*)(ws+RWB_OFF))[dst] = ldb<M>(rw, i);
    }
    else if (i < 36864)  ((u16*)(ws+C1B_OFF))[i-32768] = ldb<M>(c1w, i-32768);
    else if (i < 45056)  ((u16*)(ws+EMBB_OFF))[i-36864] = ldb<M>(ew, i-36864);
    else if (i < 53248)  ((u16*)(ws+OUTB_OFF))[i-45056] = ldb<M>(ow, i-45056);
    else if (i < 126976) {
        int j = i-53248; int o = j/288, k = j - o*288;
        int tap = k>>5, ic = k&31;
        u16 v = 0;
        if (o < 200) v = ldb<M>(c2w, (size_t)o*288 + ic*9 + tap);
        ((u16*)(ws+C2PB_OFF))[j] = v;
    }
    else if (i < 127584) {
        int j = i-126976;
        if (j < 128) wf[RED_B+j] = ldf<M>(rb, j);
        else if (j < 160) wf[C1E_B+j-128] = ldf<M>(c1b, j-128) + ldf<M>(eb, j-128);
        else if (j < 416) { int o = j-160; wf[C2_B+o] = (o<200) ? ldf<M>(c2b,o) : 0.f; }
        else if (j < 480) wf[OUT_B+j-416] = ldf<M>(ob, j-416);
        else if (j < 544) { int c=j-480; wf[BN_SC+c] = ldf<M>(gam,c) * rsqrtf(ldf<M>(vr,c)+1e-5f); }
        else { int c=j-544; wf[BN_SH+c] = ldf<M>(bet,c) - ldf<M>(mn,c)*ldf<M>(gam,c)*rsqrtf(ldf<M>(vr,c)+1e-5f); }
    }
}

__global__ __launch_bounds__(256) void k_prep(
    const void* rw, const void* rb, const void* c1w, const void* c1b,
    const void* c2w, const void* c2b, const void* ew, const void* eb,
    const void* ow, const void* ob, const void* gam, const void* bet,
    const void* mn, const void* vr, char* ws, const u32* __restrict__ flag)
{
    if (*flag) prep_body<1>(rw,rb,c1w,c1b,c2w,c2b,ew,eb,ow,ob,gam,bet,mn,vr,ws);
    else       prep_body<0>(rw,rb,c1w,c1b,c2w,c2b,ew,eb,ow,ob,gam,bet,mn,vr,ws);
}

// ---------------- fused reduce + mix ----------------
// grid 2048, 256 thr: one 64-px chunk per block.
//  P0 stage concat(ps(hi),lo) 256ch -> At
//  P1 reduce MFMA -> cat2 (global, for k_inv) + cat2_l (LDS)
//  P2 stage emb 256ch -> At (reused)
//  P3 mix MFMA, K=24 steps split across wave pairs (q2)
//  P4 partner-acc combine via LDS -> mixt
// launch_bounds(256,2): VGPR cap 256 so the compiler can hoist the unrolled
// staging loads (at cap 170 it settled at 80 regs and serialized them).
template<int M>
__device__ __forceinline__ void rm_body(
    const void* __restrict__ hi, const void* __restrict__ lo, const void* __restrict__ emb,
    const u16* __restrict__ rwB, const u16* __restrict__ c1B, const u16* __restrict__ embB,
    const float* __restrict__ wf, u16* __restrict__ cat2, u16* __restrict__ mixt,
    u16* At, u16* c2l)
{
    const int tid = threadIdx.x, wvi = tid>>6, lane = tid&63;
    const int col = lane&31, q = lane>>5;
    const int gpx = blockIdx.x*64;
    const int b = gpx>>14, p0 = gpx&16383;
    const int h = p0>>7, w0 = p0&127;
    const int co = tid>>3, po = tid&7;   // channel-octet 0..31, pixel-octet 0..7

    // ---- P0: stage concat into At ----
    {
        u32 W[8][4];
        if (co < 28) {
            u32 R[8][4];
            load8x8<M>(lo, ((size_t)(b*224 + 8*co))*HW + p0 + 8*po, HW, R);
#pragma unroll
            for (int p=0;p<8;p++){
                const int u = p>>1, hf = p&1;
#pragma unroll
                for (int m=0;m<4;m++){
                    u32 A0 = R[2*m][u], A1 = R[2*m+1][u];
                    W[p][m] = hf ? ((A0>>16) | (A1 & 0xffff0000u))
                                 : ((A0 & 0xffffu) | (A1<<16));
                }
            }
            const int ch = co + 4;
#pragma unroll
            for (int p=0;p<8;p++){
                int pg = 8*po + p;
                __builtin_memcpy(At + pg*264 + ((ch ^ swz(pg))<<3), &W[p][0], 16);
            }
        } else {
            const int cc0 = (co-28)*8, h2 = (h&1)*2;
            u32 E[8][2], O[8][2];
            if (M==1){
#pragma unroll
                for (int j=0;j<8;j++){
                    int hc = (cc0+j)*4 + h2;
                    size_t src = ((size_t)(b*128 + hc))*4096 + (size_t)(h>>1)*64 + (w0>>1) + 4*po;
                    __builtin_memcpy(&E[j][0], (const u16*)hi + src, 8);
                    __builtin_memcpy(&O[j][0], (const u16*)hi + src + 4096, 8);
                }
            } else {
                float rE[8][4], rO[8][4];
#pragma unroll
                for (int j=0;j<8;j++){
                    int hc = (cc0+j)*4 + h2;
                    size_t src = ((size_t)(b*128 + hc))*4096 + (size_t)(h>>1)*64 + (w0>>1) + 4*po;
                    __builtin_memcpy(&rE[j][0], (const float*)hi + src, 16);
                    __builtin_memcpy(&rO[j][0], (const float*)hi + src + 4096, 16);
                }
#pragma unroll
                for (int j=0;j<8;j++){
                    E[j][0] = pk2(rE[j][0], rE[j][1]); E[j][1] = pk2(rE[j][2], rE[j][3]);
                    O[j][0] = pk2(rO[j][0], rO[j][1]); O[j][1] = pk2(rO[j][2], rO[j][3]);
                }
            }
#pragma unroll
            for (int p=0;p<8;p++){
                const int k = p>>1, u = k>>1, hf = k&1;
#pragma unroll
                for (int m=0;m<4;m++){
                    u32 A0, A1;
                    if (p&1){ A0 = O[2*m][u]; A1 = O[2*m+1][u]; }
                    else    { A0 = E[2*m][u]; A1 = E[2*m+1][u]; }
                    W[p][m] = hf ? ((A0>>16) | (A1 & 0xffff0000u))
                                 : ((A0 & 0xffffu) | (A1<<16));
                }
            }
            const int ch = co - 28;
#pragma unroll
            for (int p=0;p<8;p++){
                int pg = 8*po + p;
                __builtin_memcpy(At + pg*264 + ((ch ^ swz(pg))<<3), &W[p][0], 16);
            }
        }
    }
    __syncthreads();   // A: At(concat) ready

    // ---- P1: reduce MFMA (wave = 32px x 64oc) ----
    {
        const int rt = (wvi>>1)*32, nc0 = (wvi&1)*64;
        const int pp = rt + col, sw = swz(pp);
        const u16* arow = At + pp*264;
        const int ot0 = (wvi&1)*2;

        f32x16 acc0, acc1;
#pragma unroll
        for (int r=0;r<16;r++){ acc0[r]=0.f; acc1[r]=0.f; }

        short8 Bb[2][8];
#pragma unroll
        for (int nt=0;nt<2;nt++)
#pragma unroll
        for (int s=0;s<8;s++)
            __builtin_memcpy(&Bb[nt][s], rwB + (((size_t)((ot0+nt)*16 + s))*64 + lane)*8, 16);
#pragma unroll
        for (int s=0;s<8;s++){
            short8 a; __builtin_memcpy(&a, arow + (((2*s+q)^sw)<<3), 16);
            acc0 = __builtin_amdgcn_mfma_f32_32x32x16_bf16(a, Bb[0][s], acc0, 0,0,0);
            acc1 = __builtin_amdgcn_mfma_f32_32x32x16_bf16(a, Bb[1][s], acc1, 0,0,0);
        }
#pragma unroll
        for (int nt=0;nt<2;nt++)
#pragma unroll
        for (int s=0;s<8;s++)
            __builtin_memcpy(&Bb[nt][s], rwB + (((size_t)((ot0+nt)*16 + 8+s))*64 + lane)*8, 16);
#pragma unroll
        for (int s=8;s<16;s++){
            short8 a; __builtin_memcpy(&a, arow + (((2*s+q)^sw)<<3), 16);
            acc0 = __builtin_amdgcn_mfma_f32_32x32x16_bf16(a, Bb[0][s-8], acc0, 0,0,0);
            acc1 = __builtin_amdgcn_mfma_f32_32x32x16_bf16(a, Bb[1][s-8], acc1, 0,0,0);
        }

#pragma unroll
        for (int nt=0; nt<2; nt++){
            int oc = nc0 + nt*32 + col;
            float bias = wf[RED_B + oc];
#pragma unroll
            for (int r=0;r<16;r++){
                int row = (r&3) + 8*(r>>2) + 4*q;
                int px = rt + row;
                u16 bv = f2bf((nt ? acc1[r] : acc0[r]) + bias);
                cat2[((size_t)(gpx + px))*128 + oc] = bv;
                c2l[px*136 + (((oc>>3) ^ swz(px))<<3) + (oc&7)] = bv;
            }
        }
    }

    // ---- P2: stage emb into At (issue loads, then barrier, then write) ----
    {
        u32 R[8][4];
        load8x8<M>(emb, ((size_t)(b*256 + 8*co))*HW + p0 + 8*po, HW, R);
        u32 W[8][4];
#pragma unroll
        for (int p=0;p<8;p++){
            const int u = p>>1, hf = p&1;
#pragma unroll
            for (int m=0;m<4;m++){
                u32 A0 = R[2*m][u], A1 = R[2*m+1][u];
                W[p][m] = hf ? ((A0>>16) | (A1 & 0xffff0000u))
                             : ((A0 & 0xffffu) | (A1<<16));
            }
        }
        __syncthreads();   // B: concat reads + c2l writes complete
#pragma unroll
        for (int p=0;p<8;p++){
            int pg = 8*po + p;
            __builtin_memcpy(At + pg*264 + ((co ^ swz(pg))<<3), &W[p][0], 16);
        }
    }
    __syncthreads();   // C: At(emb) + c2l ready

    // ---- P3: mix MFMA, K-split across wave pairs ----
    const int rt2 = wvi>>1, q2 = wvi&1;
    const int pp2 = rt2*32 + col, sw2 = swz(pp2);
    const u16* arow136 = c2l + pp2*136;
    const u16* arow264 = At + pp2*264;

    f32x16 macc;
#pragma unroll
    for (int r=0;r<16;r++) macc[r]=0.f;

    if (q2 == 0){
        short8 Bc[8];
#pragma unroll
        for (int s=0;s<8;s++)
            __builtin_memcpy(&Bc[s], c1B + (size_t)col*128 + s*16 + q*8, 16);
#pragma unroll
        for (int s=0;s<8;s++){
            short8 a; __builtin_memcpy(&a, arow136 + (((2*s+q)^sw2)<<3), 16);
            macc = __builtin_amdgcn_mfma_f32_32x32x16_bf16(a, Bc[s], macc, 0,0,0);
        }
        short8 Be[4];
#pragma unroll
        for (int s=0;s<4;s++)
            __builtin_memcpy(&Be[s], embB + (size_t)col*256 + s*16 + q*8, 16);
#pragma unroll
        for (int s=0;s<4;s++){
            short8 a; __builtin_memcpy(&a, arow264 + (((2*s+q)^sw2)<<3), 16);
            macc = __builtin_amdgcn_mfma_f32_32x32x16_bf16(a, Be[s], macc, 0,0,0);
        }
    } else {
        short8 Be[12];
#pragma unroll
        for (int s=0;s<12;s++)
            __builtin_memcpy(&Be[s], embB + (size_t)col*256 + (4+s)*16 + q*8, 16);
#pragma unroll
        for (int s=0;s<12;s++){
            int ks = 4 + s;
            short8 a; __builtin_memcpy(&a, arow264 + (((2*ks+q)^sw2)<<3), 16);
            macc = __builtin_amdgcn_mfma_f32_32x32x16_bf16(a, Be[s], macc, 0,0,0);
        }
    }
    __syncthreads();   // D: all MFMA reads of At/c2l done

    // ---- P4: combine partner accs via LDS (reuse At as f32 buffer) ----
    float* exch = (float*)At;
    if (q2 == 1){
#pragma unroll
        for (int r=0;r<16;r++){
            int row = (r&3) + 8*(r>>2) + 4*q;
            exch[rt2*1024 + row*32 + col] = macc[r];
        }
    }
    __syncthreads();   // E
    if (q2 == 0){
        float bias = wf[C1E_B + col];
#pragma unroll
        for (int r=0;r<16;r++){
            int row = (r&3) + 8*(r>>2) + 4*q;
            float v = macc[r] + exch[rt2*1024 + row*32 + col] + bias;
            mixt[((size_t)(gpx + rt2*32 + row))*32 + col] = f2bf(lrelu(v));
        }
    }
}

__global__ __launch_bounds__(256,2) void k_rm(
    const void* __restrict__ hi, const void* __restrict__ lo, const void* __restrict__ emb,
    const u16* __restrict__ rwB, const u16* __restrict__ c1B, const u16* __restrict__ embB,
    const float* __restrict__ wf, u16* __restrict__ cat2, u16* __restrict__ mixt,
    const u32* __restrict__ flag)
{
    __shared__ u16 At[64*264];    // 33792 B (concat, then emb, then f32 exch)
    __shared__ u16 c2l[64*136];   // 17408 B (cat2 tile, swizzled)
    if (*flag) rm_body<1>(hi, lo, emb, rwB, c1B, embB, wf, cat2, mixt, At, c2l);
    else       rm_body<0>(hi, lo, emb, rwB, c1B, embB, wf, cat2, mixt, At, c2l);
}

// ---------------- fused conv2 + involution + out conv + BN + lrelu ----------------
template<int M>
__device__ __forceinline__ void inv_body(
    const u16* __restrict__ cat2, const u16* __restrict__ mixt,
    const u16* __restrict__ c2B, const u16* __restrict__ outB,
    const float* __restrict__ wf, void* __restrict__ out,
    u16* halo_m, u16* wgt_l, u16* halo_c, u16* og)
{
    const int tid = threadIdx.x, wvi = tid>>6, lane = tid&63;
    const int col = lane&31, q = lane>>5;
    const int b = blockIdx.y, ty = blockIdx.x>>3, tx = blockIdx.x&7;
    const int py = tid>>4, px = tid&15;

    f32x16 acc[2][2];
#pragma unroll
    for (int i=0;i<2;i++)
#pragma unroll
    for (int j=0;j<2;j++)
#pragma unroll
    for (int r=0;r<16;r++) acc[i][j][r] = 0.f;

    // ---- stage mixt halo 18x18 x 32ch, stride 40 u16 ----
#pragma unroll
    for (int i=0;i<6;i++){
        int idx = tid + i*256;
        if (idx < 1296){
            int point = idx>>2, cq = idx&3;
            int y = ty*16 + point/18 - 1, x = tx*16 + point%18 - 1;
            short8 v;
            if (y>=0 && y<128 && x>=0 && x<128)
                __builtin_memcpy(&v, mixt + ((size_t)(b*HW + y*128 + x))*32 + cq*8, 16);
            else { short z=0; v = (short8){z,z,z,z,z,z,z,z}; }
            *(short8*)(halo_m + point*40 + cq*8) = v;
        }
    }
    __syncthreads();   // halo_m ready

#pragma unroll 1
    for (int g=0; g<8; g++){
        __syncthreads();   // prev group's halo_c/wgt_l/og reads complete

        const int o = g*25 + col;
        short8 Bf[18];
#pragma unroll
        for (int s=0;s<18;s++)
            __builtin_memcpy(&Bf[s], c2B + (size_t)o*288 + s*16 + q*8, 16);

#pragma unroll
        for (int i=0;i<4;i++){
            int idx = tid + i*256;
            if (idx < 800){
                int point = idx>>1, cq = idx&1;
                int y = ty*16 + point/20 - 2, x = tx*16 + point%20 - 2;
                short8 v;
                if (y>=0 && y<128 && x>=0 && x<128)
                    __builtin_memcpy(&v, cat2 + ((size_t)(b*HW + y*128 + x))*128 + g*16 + cq*8, 16);
                else { short z=0; v = (short8){z,z,z,z,z,z,z,z}; }
                *(short8*)(halo_c + point*16 + cq*8) = v;
            }
        }

        f32x16 c0, c1;
#pragma unroll
        for (int r=0;r<16;r++){ c0[r]=0.f; c1[r]=0.f; }
        const int p0 = wvi*64 + col, p1 = p0 + 32;
        const int pya = p0>>4, pxa = p0&15, pyb = p1>>4, pxb = p1&15;
#pragma unroll
        for (int s=0;s<18;s++){
            int tap = s>>1, ih = s&1;
            int dy = tap/3, dx = tap%3;
            short8 a0, a1;
            __builtin_memcpy(&a0, halo_m + ((pya+dy)*18 + pxa+dx)*40 + ih*16 + q*8, 16);
            __builtin_memcpy(&a1, halo_m + ((pyb+dy)*18 + pxb+dx)*40 + ih*16 + q*8, 16);
            c0 = __builtin_amdgcn_mfma_f32_32x32x16_bf16(a0, Bf[s], c0, 0,0,0);
            c1 = __builtin_amdgcn_mfma_f32_32x32x16_bf16(a1, Bf[s], c1, 0,0,0);
        }
        {
            float bias = wf[C2_B + o];
#pragma unroll
            for (int rt2=0; rt2<2; rt2++){
                int mb = wvi*64 + rt2*32;
#pragma unroll
                for (int r=0;r<16;r+=2){
                    int row0 = (r&3) + 8*(r>>2) + 4*q;
                    float v0 = (rt2 ? c1[r]   : c0[r])   + bias;
                    float v1 = (rt2 ? c1[r+1] : c0[r+1]) + bias;
                    u32 pkv = (u32)f2bf(v0) | ((u32)f2bf(v1)<<16);
                    *(u32*)(wgt_l + (size_t)col*264 + mb + row0) = pkv;
                }
            }
        }
        __syncthreads();   // halo_c + wgt_l ready

        float wvv[25];
#pragma unroll
        for (int t=0;t<25;t++) wvv[t] = bf2f(wgt_l[t*264 + tid]);

        float a16[16];
#pragma unroll
        for (int cc=0;cc<16;cc++) a16[cc]=0.f;
#pragma unroll
        for (int t=0;t<25;t++){
            int dy = t/5, dx = t%5;
            u32 vv[8];
            __builtin_memcpy(vv, halo_c + ((py+dy)*20 + px+dx)*16, 32);
            float wt = wvv[t];
#pragma unroll
            for (int r=0;r<8;r++){
                u32 u = vv[r];
                u32 ulo = u<<16, uhi = u & 0xffff0000u;
                float x0, x1;
                __builtin_memcpy(&x0,&ulo,4); __builtin_memcpy(&x1,&uhi,4);
                a16[2*r]   += wt*x0;
                a16[2*r+1] += wt*x1;
            }
        }
        u32 pk[8];
#pragma unroll
        for (int r=0;r<8;r++) pk[r] = (u32)f2bf(a16[2*r]) | ((u32)f2bf(a16[2*r+1])<<16);
        __builtin_memcpy(og + tid*16, pk, 32);
        __syncthreads();   // og ready

        short8 bo0, bo1;
        __builtin_memcpy(&bo0, outB + (size_t)(col)*128      + g*16 + q*8, 16);
        __builtin_memcpy(&bo1, outB + (size_t)(32+col)*128   + g*16 + q*8, 16);
#pragma unroll
        for (int rt2=0; rt2<2; rt2++){
            int prow = (wvi*2 + rt2)*32 + col;
            short8 a; __builtin_memcpy(&a, og + prow*16 + q*8, 16);
            acc[rt2][0] = __builtin_amdgcn_mfma_f32_32x32x16_bf16(a, bo0, acc[rt2][0], 0,0,0);
            acc[rt2][1] = __builtin_amdgcn_mfma_f32_32x32x16_bf16(a, bo1, acc[rt2][1], 0,0,0);
        }
    }
#pragma unroll
    for (int rt2=0; rt2<2; rt2++)
#pragma unroll
    for (int nt=0; nt<2; nt++){
        int oc = nt*32 + col;
        float bias = wf[OUT_B+oc], sc = wf[BN_SC+oc], sh = wf[BN_SH+oc];
#pragma unroll
        for (int r=0;r<16;r++){
            int row = (r&3) + 8*(r>>2) + 4*q;
            int p = (wvi*2 + rt2)*32 + row;
            int yy = ty*16 + (p>>4), xx = tx*16 + (p&15);
            float v = lrelu((acc[rt2][nt][r] + bias)*sc + sh);
            size_t oidx = ((size_t)(b*64 + oc))*HW + yy*128 + xx;
            if (M==1) ((u16*)out)[oidx] = f2bf(v);
            else ((float*)out)[oidx] = v;
        }
    }
}

__global__ __launch_bounds__(256,2) void k_inv(
    const u16* __restrict__ cat2, const u16* __restrict__ mixt,
    const u16* __restrict__ c2B, const u16* __restrict__ outB,
    const float* __restrict__ wf, void* __restrict__ out, const u32* __restrict__ flag)
{
    __shared__ u16 halo_m[324*40];   // 25920 B
    __shared__ u16 wgt_l[32*264];    // 16896 B
    __shared__ u16 halo_c[400*16];   // 12800 B
    __shared__ u16 og[256*16];       //  8192 B  -> total 63808 B
    if (*flag) inv_body<1>(cat2, mixt, c2B, outB, wf, out, halo_m, wgt_l, halo_c, og);
    else       inv_body<0>(cat2, mixt, c2B, outB, wf, out, halo_m, wgt_l, halo_c, og);
}

extern "C" void kernel_launch(void* const* d_in, const int* in_sizes, int n_in,
                              void* d_out, int out_size, void* d_ws, size_t ws_size,
                              hipStream_t stream) {
    const void* hi  = d_in[0];
    const void* lo  = d_in[1];
    const void* emb = d_in[2];
    char* ws = (char*)d_ws;
    float* wf = (float*)ws;
    u32* flag = (u32*)(ws + FLAG_OFF);
    u16* cat2 = (u16*)(ws + CAT2_OFF);
    u16* mixt = (u16*)(ws + MIX_OFF);

    detect_kernel<<<1, 64, 0, stream>>>(emb, flag);

    k_prep<<<499,256,0,stream>>>(d_in[3],d_in[4],d_in[5],d_in[6],d_in[7],d_in[8],
        d_in[9],d_in[10],d_in[11],d_in[12],d_in[13],d_in[14],d_in[15],d_in[16], ws, flag);

    k_rm<<<2048,256,0,stream>>>(hi, lo, emb, (const u16*)(ws+RWB_OFF),
                                (const u16*)(ws+C1B_OFF), (const u16*)(ws+EMBB_OFF),
                                wf, cat2, mixt, flag);

    k_inv<<<dim3(64,8),256,0,stream>>>(cat2, mixt, (const u16*)(ws+C2PB_OFF),
                                       (const u16*)(ws+OUTB_OFF), wf, d_out, flag);
}